// Round 4
// baseline (80.875 us; speedup 1.0000x reference)
//
#include <hip/hip_runtime.h>

#define NRULE 100
#define NB    32
#define NE    15000
#define NTOT  (NB * NE)   // 480000
#define HD    16
#define KMID  128
#define LN_EPS 1e-5f

// Precompute c[k] = b1[k] + sum_h rel[h] * W1[(H+h)*128 + k]  (rel = relation_emb[all_r[0]])
__global__ void precompute_c_kernel(const long long* __restrict__ all_r,
                                    const float* __restrict__ relemb,
                                    const float* __restrict__ W1,
                                    const float* __restrict__ b1,
                                    float* __restrict__ cvec)
{
    const int k = threadIdx.x;
    if (k >= KMID) return;
    const int r = (int)all_r[0];
    float t = b1[k];
#pragma unroll
    for (int h = 0; h < HD; ++h)
        t = fmaf(relemb[r * HD + h], W1[(HD + h) * KMID + k], t);
    cvec[k] = t;
}

// 4 elements per thread, int4 (16B/lane) loads of rc.
__global__ __launch_bounds__(256) void predictor_main_kernel(
    const int*   __restrict__ rc,     // [R, B*E]
    const float* __restrict__ remb,   // [R, 16]
    const float* __restrict__ ln_g,
    const float* __restrict__ ln_b,
    const float* __restrict__ W1,     // [32, 128] row-major; rows 0..15 used here
    const float* __restrict__ W2,     // [128]
    const float* __restrict__ b2,     // [1]
    const float* __restrict__ bias,   // [E]
    const float* __restrict__ cvec,   // [128] precomputed
    float* __restrict__ out)          // [B*E]
{
    const int tid  = blockIdx.x * blockDim.x + threadIdx.x;
    const int base = tid * 4;
    if (base >= NTOT) return;

    float acc[4][HD];
#pragma unroll
    for (int e = 0; e < 4; ++e)
#pragma unroll
        for (int h = 0; h < HD; ++h) acc[e][h] = 0.f;
    float ws[4] = {0.f, 0.f, 0.f, 0.f};

    const int* rcp = rc + base;
#pragma unroll 2
    for (int r0 = 0; r0 < NRULE; r0 += 5) {
        int4 v[5];
#pragma unroll
        for (int i = 0; i < 5; ++i)
            v[i] = *reinterpret_cast<const int4*>(rcp + (r0 + i) * NTOT);  // 16B/lane
#pragma unroll
        for (int i = 0; i < 5; ++i) {
            const float f0 = (float)v[i].x;
            const float f1 = (float)v[i].y;
            const float f2 = (float)v[i].z;
            const float f3 = (float)v[i].w;
            ws[0] += f0; ws[1] += f1; ws[2] += f2; ws[3] += f3;
#pragma unroll
            for (int h = 0; h < HD; ++h) {
                const float w = remb[(r0 + i) * HD + h];   // wave-uniform -> SGPR
                acc[0][h] = fmaf(f0, w, acc[0][h]);
                acc[1][h] = fmaf(f1, w, acc[1][h]);
                acc[2][h] = fmaf(f2, w, acc[2][h]);
                acc[3][h] = fmaf(f3, w, acc[3][h]);
            }
        }
    }

    float o[4];
#pragma unroll
    for (int e = 0; e < 4; ++e) {
        // LayerNorm over H=16 + ReLU, in place
        float mu = 0.f;
#pragma unroll
        for (int h = 0; h < HD; ++h) mu += acc[e][h];
        mu *= (1.f / HD);
        float var = 0.f;
#pragma unroll
        for (int h = 0; h < HD; ++h) {
            const float d = acc[e][h] - mu;
            var = fmaf(d, d, var);
        }
        var *= (1.f / HD);
        const float ri = rsqrtf(var + LN_EPS);
#pragma unroll
        for (int h = 0; h < HD; ++h)
            acc[e][h] = fmaxf(fmaf((acc[e][h] - mu) * ri, ln_g[h], ln_b[h]), 0.f);

        // MLP: o = W2^T relu(W1[0:16]^T acc + c) + b2, mid dim chunked by 8
        float oo = b2[0];
#pragma unroll 1
        for (int kc = 0; kc < KMID; kc += 8) {
            float t[8];
#pragma unroll
            for (int kk = 0; kk < 8; ++kk) t[kk] = cvec[kc + kk];
#pragma unroll
            for (int h = 0; h < HD; ++h) {
                const float a = acc[e][h];
#pragma unroll
                for (int kk = 0; kk < 8; ++kk)
                    t[kk] = fmaf(a, W1[h * KMID + kc + kk], t[kk]);
            }
#pragma unroll
            for (int kk = 0; kk < 8; ++kk)
                oo = fmaf(fmaxf(t[kk], 0.f), W2[kc + kk], oo);
        }
        o[e] = (ws[e] > 0.f) ? oo : 0.f;
    }

    const int m = base % NE;                       // base%4==0, NE%4==0 -> m+3 < NE, 16B aligned
    const float4 bv = *reinterpret_cast<const float4*>(bias + m);
    float4 res;
    res.x = o[0] + bv.x;
    res.y = o[1] + bv.y;
    res.z = o[2] + bv.z;
    res.w = o[3] + bv.w;
    *reinterpret_cast<float4*>(out + base) = res;
}

extern "C" void kernel_launch(void* const* d_in, const int* in_sizes, int n_in,
                              void* d_out, int out_size, void* d_ws, size_t ws_size,
                              hipStream_t stream)
{
    const long long* all_r = (const long long*)d_in[1];
    const int*   rc     = (const int*)d_in[2];
    const float* remb   = (const float*)d_in[3];
    const float* relemb = (const float*)d_in[4];
    const float* ln_g   = (const float*)d_in[5];
    const float* ln_b   = (const float*)d_in[6];
    const float* W1     = (const float*)d_in[7];
    const float* b1     = (const float*)d_in[8];
    const float* W2     = (const float*)d_in[9];
    const float* b2     = (const float*)d_in[10];
    const float* bias   = (const float*)d_in[11];
    float* out  = (float*)d_out;
    float* cvec = (float*)d_ws;

    hipLaunchKernelGGL(precompute_c_kernel, dim3(1), dim3(128), 0, stream,
                       all_r, relemb, W1, b1, cvec);

    const int threads = (NTOT + 3) / 4;              // 120000
    const int blocks  = (threads + 255) / 256;       // 469
    hipLaunchKernelGGL(predictor_main_kernel, dim3(blocks), dim3(256), 0, stream,
                       rc, remb, ln_g, ln_b, W1, W2, b2, bias, cvec, out);
}